// Round 5
// baseline (129.870 us; speedup 1.0000x reference)
//
#include <hip/hip_runtime.h>

#define T_LEN 262144
#define B_SZ 8
#define CHUNK 4096
#define HALO 4096
#define NTHREADS 1024
#define NGROUPS ((CHUNK + HALO) / 4)    // 2048 float4-groups per block frame
#define CHUNKS_PER_ROW (T_LEN / CHUNK)  // 64
#define NBLOCKS (B_SZ * CHUNKS_PER_ROW) // 512 -> 2 blocks/CU
#define LOG2E 1.4426950408889634f
#define NEG2LOG2E (-2.8853900817779268f)
#define NEGLOG2E  (-1.4426950408889634f)

typedef float f32x4 __attribute__((ext_vector_type(4)));

__device__ __forceinline__ float frcp(float x)  { return __builtin_amdgcn_rcpf(x); }
__device__ __forceinline__ float fexp2(float x) { return __builtin_amdgcn_exp2f(x); }
__device__ __forceinline__ f32x4 splat(float s) { f32x4 r = {s, s, s, s}; return r; }
// scalar-broadcast fma on f32x4 -> backend can fuse into v_pk_fma_f32 pairs
__device__ __forceinline__ f32x4 sfma(float s, f32x4 v, f32x4 a) {
    return __builtin_elementwise_fma(splat(s), v, a);
}
// bf16x2 pack (truncating) via single v_perm_b32 per word; unpack leaves the
// neighbor's bits in the low mantissa (<=2^-9 relative noise, ~bf16 rounding)
__device__ __forceinline__ uint2 pk4(f32x4 v) {
    uint2 u;
    u.x = __builtin_amdgcn_perm(__float_as_uint(v.y), __float_as_uint(v.x), 0x07060302u);
    u.y = __builtin_amdgcn_perm(__float_as_uint(v.w), __float_as_uint(v.z), 0x07060302u);
    return u;
}
__device__ __forceinline__ f32x4 up4(uint2 u) {
    f32x4 r;
    r.x = __uint_as_float(u.x << 16);
    r.y = __uint_as_float(u.x);
    r.z = __uint_as_float(u.y << 16);
    r.w = __uint_as_float(u.y);
    return r;
}
// o = tanh(a)*sigmoid(b), af = -2*log2e*a, ag = -log2e*b pre-scaled:
// E1=2^af=e^{-2a}, E2=2^ag=e^{-b}; o = (1-E1)/((1+E1)(1+E2))
__device__ __forceinline__ f32x4 gate4(f32x4 af, f32x4 ag) {
    f32x4 E1, E2;
    E1.x = fexp2(af.x); E1.y = fexp2(af.y); E1.z = fexp2(af.z); E1.w = fexp2(af.w);
    E2.x = fexp2(ag.x); E2.y = fexp2(ag.y); E2.z = fexp2(ag.z); E2.w = fexp2(ag.w);
    f32x4 d1  = E1 + splat(1.0f);
    f32x4 den = __builtin_elementwise_fma(E2, d1, d1);
    f32x4 num = splat(1.0f) - E1;
    f32x4 r;
    r.x = num.x * frcp(den.x); r.y = num.y * frcp(den.y);
    r.z = num.z * frcp(den.z); r.w = num.w * frcp(den.w);
    return r;
}
// conv1->relu->conv2->relu->mu-law expand; exp(|b|*ln256) == exp2(|b|*8)
__device__ __forceinline__ float mulaw(float v, float c1wv, float c1bv, float c2wv, float c2bv) {
    float a  = __builtin_fmaf(c1wv, fmaxf(v, 0.0f), c1bv);
    float b2 = __builtin_fmaf(c2wv, fmaxf(a, 0.0f), c2bv);
    float m  = fexp2(fabsf(b2) * 8.0f) - 1.0f;
    return copysignf(m * (1.0f / 255.0f), b2);
}

// One dilation cycle (10 layers, d=1..512). Thread owns 2 float4 groups
// (w=0: halo, w=1: valid) in fp32 registers; LDS holds bf16x2-packed taps,
// double-buffered, ONE barrier per layer. Inter-stage h handoff is packed
// bf16 (uint2). Reach-based halo skip: layer k's output is only needed at
// halo groups G >= 2^(k+1) (exact receptive-field arithmetic), so threads
// tid < 2<<k skip their w=0 work; reads by needed groups never touch
// skipped (stale) groups, and no index can underflow in the layer loop.
// Zero padding: global t<0 <=> (chunk==0 && w==0).
template <int STAGE>
__global__ __launch_bounds__(NTHREADS, 8)
void stage_kernel(const void* __restrict__ in_,
                  const float* __restrict__ cw, const float* __restrict__ cb,
                  const float* __restrict__ fw, const float* __restrict__ fb,
                  const float* __restrict__ gw, const float* __restrict__ gb,
                  const float* __restrict__ rw, const float* __restrict__ rb,
                  uint2* __restrict__ hout, float* __restrict__ skio,
                  const float* __restrict__ c1w, const float* __restrict__ c1b,
                  const float* __restrict__ c2w, const float* __restrict__ c2b,
                  float2* __restrict__ blockstats)
{
    __shared__ uint2 bufl[2][NGROUPS];       // 2 x 16 KB bf16x2 tap buffers
    __shared__ float red[NTHREADS / 64];

    const int tid = threadIdx.x;
    const int bid = blockIdx.x;
    const int row = bid / CHUNKS_PER_ROW;
    const int chunk = bid % CHUNKS_PER_ROW;
    const int rowbase = row * T_LEN;
    const int base_t = chunk * CHUNK;
    const bool first = (chunk == 0);

    // ---- load own groups (fp32 regs) + publish packed taps to buf 0 ----
    f32x4 h[2];
    if (STAGE == 0) {
        const float* inb = (const float*)in_ + rowbase + base_t - HALO;
        #pragma unroll
        for (int w = 0; w < 2; ++w) {
            int G = tid + w * NTHREADS;
            if (w == 0 && first) h[w] = splat(0.0f);
            else                 h[w] = *(const f32x4*)(inb + 4 * G);
            bufl[0][G] = pk4(h[w]);
        }
    } else {
        const uint2* inb = (const uint2*)in_ + ((rowbase + base_t - HALO) >> 2);
        #pragma unroll
        for (int w = 0; w < 2; ++w) {
            int G = tid + w * NTHREADS;
            uint2 u = (w == 0 && first) ? make_uint2(0u, 0u) : inb[G];
            bufl[0][G] = u;
            h[w] = up4(u);
        }
    }
    f32x4 sk;
    if (STAGE == 0) sk = splat(0.0f);
    else            sk = *(const f32x4*)(skio + rowbase + base_t + 4 * tid);
    __syncthreads();

    int c = 0;
    if (STAGE == 0) {
        // causal conv (d=1); weight for tap distance m is cw[4-m]
        const float c0 = cw[4], c1 = cw[3], c2 = cw[2], c3 = cw[1], c4 = cw[0];
        const float bb = cb[0];
        #pragma unroll
        for (int w = 0; w < 2; ++w) {
            int G = tid + w * NTHREADS;
            int gm = G - 1; if (w == 0) gm = gm < 0 ? 0 : gm;  // junk-in-halo OK
            f32x4 T = up4(bufl[0][gm]);
            f32x4 hw = h[w];
            f32x4 t1 = __builtin_shufflevector(T, hw, 3, 4, 5, 6);
            f32x4 t2 = __builtin_shufflevector(T, hw, 2, 3, 4, 5);
            f32x4 t3 = __builtin_shufflevector(T, hw, 1, 2, 3, 4);
            f32x4 acc = sfma(c0, hw, splat(bb));
            acc = sfma(c1, t1, acc);
            acc = sfma(c2, t2, acc);
            acc = sfma(c3, t3, acc);
            acc = sfma(c4, T, acc);
            if (w == 0 && first) acc = splat(0.0f);
            h[w] = acc;
            bufl[1][G] = pk4(acc);
        }
        __syncthreads();
        c = 1;
    }

    // ---- 10 dilated gated layers, one barrier each ----
    #pragma unroll
    for (int k = 0; k < 10; ++k) {
        const int d = 1 << k;
        const int L = STAGE * 10 + k;
        const float* fwL = fw + 5 * L;
        const float* gwL = gw + 5 * L;
        const float wf0 = fwL[4] * NEG2LOG2E, wf1 = fwL[3] * NEG2LOG2E,
                    wf2 = fwL[2] * NEG2LOG2E, wf3 = fwL[1] * NEG2LOG2E,
                    wf4 = fwL[0] * NEG2LOG2E;
        const float wg0 = gwL[4] * NEGLOG2E, wg1 = gwL[3] * NEGLOG2E,
                    wg2 = gwL[2] * NEGLOG2E, wg3 = gwL[1] * NEGLOG2E,
                    wg4 = gwL[0] * NEGLOG2E;
        const float fbv = fb[L] * NEG2LOG2E, gbv = gb[L] * NEGLOG2E;
        const float rwv = rw[L], rbv = rb[L];

        #pragma unroll
        for (int w = 0; w < 2; ++w) {
            if (w == 0 && k == 9) continue;          // halo never needed after last layer
            const int G = tid + w * NTHREADS;
            if (w == 0 && tid < (2 << k)) continue;  // reach expired for this group
            f32x4 hw = h[w];
            f32x4 t1, t2, t3, t4;
            if (d >= 4) {
                const int DG = d >> 2;               // taps stay group-aligned
                t1 = up4(bufl[c][G - DG]);
                t2 = up4(bufl[c][G - 2 * DG]);
                t3 = up4(bufl[c][G - 3 * DG]);
                t4 = up4(bufl[c][G - 4 * DG]);
            } else if (d == 1) {
                f32x4 T = up4(bufl[c][G - 1]);
                t1 = __builtin_shufflevector(T, hw, 3, 4, 5, 6);
                t2 = __builtin_shufflevector(T, hw, 2, 3, 4, 5);
                t3 = __builtin_shufflevector(T, hw, 1, 2, 3, 4);
                t4 = T;
            } else { // d == 2
                f32x4 T1 = up4(bufl[c][G - 1]);
                f32x4 T2 = up4(bufl[c][G - 2]);
                t1 = __builtin_shufflevector(T1, hw, 2, 3, 4, 5);
                t2 = T1;
                t3 = __builtin_shufflevector(T2, T1, 2, 3, 4, 5);
                t4 = T2;
            }
            f32x4 af = sfma(wf0, hw, splat(fbv));
            af = sfma(wf1, t1, af); af = sfma(wf2, t2, af);
            af = sfma(wf3, t3, af); af = sfma(wf4, t4, af);
            f32x4 ag = sfma(wg0, hw, splat(gbv));
            ag = sfma(wg1, t1, ag); ag = sfma(wg2, t2, ag);
            ag = sfma(wg3, t3, ag); ag = sfma(wg4, t4, ag);
            f32x4 o = gate4(af, ag);
            f32x4 nh = sfma(rwv, o, hw + splat(rbv));
            if (w == 0 && first) nh = splat(0.0f);   // keep t<0 padding exactly 0
            h[w] = nh;
            if (k < 9) bufl[c ^ 1][G] = pk4(nh);     // last layer never re-read
            if (w == 1) sk += o;
        }
        if (k < 9) __syncthreads();
        c ^= 1;
    }

    if (STAGE < 2) {
        hout[((rowbase + base_t) >> 2) + tid] = pk4(h[1]);   // packed bf16 handoff
        *(f32x4*)(skio + rowbase + base_t + 4 * tid) = sk;
    } else {
        // fused epilogue + per-block (max, sum-exp) stats
        const float c1wv = c1w[0], c1bv = c1b[0], c2wv = c2w[0], c2bv = c2b[0];
        f32x4 p;
        p.x = mulaw(sk.x, c1wv, c1bv, c2wv, c2bv);
        p.y = mulaw(sk.y, c1wv, c1bv, c2wv, c2bv);
        p.z = mulaw(sk.z, c1wv, c1bv, c2wv, c2bv);
        p.w = mulaw(sk.w, c1wv, c1bv, c2wv, c2bv);
        *(f32x4*)(skio + rowbase + base_t + 4 * tid) = p;

        float pmax = fmaxf(fmaxf(p.x, p.y), fmaxf(p.z, p.w));
        #pragma unroll
        for (int off = 32; off; off >>= 1) pmax = fmaxf(pmax, __shfl_xor(pmax, off, 64));
        if ((tid & 63) == 0) red[tid >> 6] = pmax;
        __syncthreads();
        float bmax = red[0];
        #pragma unroll
        for (int i = 1; i < NTHREADS / 64; ++i) bmax = fmaxf(bmax, red[i]);
        __syncthreads();   // red reused below

        float ps = fexp2((p.x - bmax) * LOG2E) + fexp2((p.y - bmax) * LOG2E)
                 + fexp2((p.z - bmax) * LOG2E) + fexp2((p.w - bmax) * LOG2E);
        #pragma unroll
        for (int off = 32; off; off >>= 1) ps += __shfl_xor(ps, off, 64);
        if ((tid & 63) == 0) red[tid >> 6] = ps;
        __syncthreads();
        if (tid == 0) {
            float s = 0.0f;
            #pragma unroll
            for (int i = 0; i < NTHREADS / 64; ++i) s += red[i];
            blockstats[bid] = make_float2(bmax, s);
        }
    }
}

// 8 blocks (one per row) x 64 threads: reduce 64 block-stats -> (rowmax, 1/rowsum)
__global__ __launch_bounds__(64)
void combine_kernel(const float2* __restrict__ bs, float2* __restrict__ rs)
{
    const int row = blockIdx.x;
    const int lane = threadIdx.x;
    float2 v = bs[row * CHUNKS_PER_ROW + lane];   // CHUNKS_PER_ROW == 64
    float bm = v.x, s = v.y;
    float m = bm;
    #pragma unroll
    for (int off = 32; off; off >>= 1) m = fmaxf(m, __shfl_xor(m, off, 64));
    float cc = s * fexp2((bm - m) * LOG2E);
    #pragma unroll
    for (int off = 32; off; off >>= 1) cc += __shfl_xor(cc, off, 64);
    if (lane == 0) rs[row] = make_float2(m, 1.0f / cc);
}

__global__ __launch_bounds__(NTHREADS)
void norm_kernel(float* __restrict__ p, const float2* __restrict__ rs)
{
    const int tid = threadIdx.x, bid = blockIdx.x;
    const int row = bid / CHUNKS_PER_ROW;
    const float2 st = rs[row];
    float* q = p + row * T_LEN + (bid % CHUNKS_PER_ROW) * CHUNK + 4 * tid;
    f32x4 v = *(const f32x4*)q;
    v.x = fexp2((v.x - st.x) * LOG2E) * st.y;
    v.y = fexp2((v.y - st.x) * LOG2E) * st.y;
    v.z = fexp2((v.z - st.x) * LOG2E) * st.y;
    v.w = fexp2((v.w - st.x) * LOG2E) * st.y;
    *(f32x4*)q = v;
}

extern "C" void kernel_launch(void* const* d_in, const int* in_sizes, int n_in,
                              void* d_out, int out_size, void* d_ws, size_t ws_size,
                              hipStream_t stream)
{
    (void)in_sizes; (void)n_in; (void)out_size; (void)ws_size;
    const float* x   = (const float*)d_in[0];
    const float* cw  = (const float*)d_in[1];
    const float* cb  = (const float*)d_in[2];
    const float* fw  = (const float*)d_in[3];
    const float* fb  = (const float*)d_in[4];
    const float* gw  = (const float*)d_in[5];
    const float* gb  = (const float*)d_in[6];
    const float* rw  = (const float*)d_in[7];
    const float* rb  = (const float*)d_in[8];
    const float* c1w = (const float*)d_in[9];
    const float* c1b = (const float*)d_in[10];
    const float* c2w = (const float*)d_in[11];
    const float* c2b = (const float*)d_in[12];
    float* out = (float*)d_out;

    const size_t NTOT = (size_t)B_SZ * T_LEN;
    uint2*  hA = (uint2*)d_ws;                                  // 4.2 MB packed bf16
    uint2*  hB = (uint2*)((char*)d_ws + NTOT * 2);              // 4.2 MB
    float2* bs = (float2*)((char*)d_ws + NTOT * 4);             // 4 KB
    float2* rs = (float2*)((char*)d_ws + NTOT * 4 + 8192);      // 64 B

    // d_out doubles as the skip accumulator between stages, then holds
    // pre-softmax values, then the final softmax output.
    stage_kernel<0><<<NBLOCKS, NTHREADS, 0, stream>>>(x,  cw, cb, fw, fb, gw, gb, rw, rb,
                                                      hA, out, c1w, c1b, c2w, c2b, bs);
    stage_kernel<1><<<NBLOCKS, NTHREADS, 0, stream>>>(hA, cw, cb, fw, fb, gw, gb, rw, rb,
                                                      hB, out, c1w, c1b, c2w, c2b, bs);
    stage_kernel<2><<<NBLOCKS, NTHREADS, 0, stream>>>(hB, cw, cb, fw, fb, gw, gb, rw, rb,
                                                      nullptr, out, c1w, c1b, c2w, c2b, bs);
    combine_kernel<<<B_SZ, 64, 0, stream>>>(bs, rs);
    norm_kernel<<<NBLOCKS, NTHREADS, 0, stream>>>(out, rs);
}

// Round 6
// 119.083 us; speedup vs baseline: 1.0906x; 1.0906x over previous
//
#include <hip/hip_runtime.h>

#define T_LEN 262144
#define B_SZ 8
#define CHUNK 4096
#define HALO 4096
#define NTHREADS 1024
#define NGROUPS ((CHUNK + HALO) / 4)    // 2048 float4-groups per block frame
#define CHUNKS_PER_ROW (T_LEN / CHUNK)  // 64
#define NBLOCKS (B_SZ * CHUNKS_PER_ROW) // 512 -> 2 blocks/CU
#define LOG2E 1.4426950408889634f
#define NEG2LOG2E (-2.8853900817779268f)
#define NEGLOG2E  (-1.4426950408889634f)

typedef float f32x4 __attribute__((ext_vector_type(4)));

__device__ __forceinline__ float frcp(float x)  { return __builtin_amdgcn_rcpf(x); }
__device__ __forceinline__ float fexp2(float x) { return __builtin_amdgcn_exp2f(x); }
__device__ __forceinline__ f32x4 splat(float s) { f32x4 r = {s, s, s, s}; return r; }
// scalar-broadcast fma on f32x4 -> backend can fuse into v_pk_fma_f32 pairs
__device__ __forceinline__ f32x4 sfma(float s, f32x4 v, f32x4 a) {
    return __builtin_elementwise_fma(splat(s), v, a);
}
// bf16x2 pack (truncating) via single v_perm_b32 per word; unpack leaves the
// neighbor's bits in the low mantissa (<=2^-9 relative noise, ~bf16 rounding)
__device__ __forceinline__ uint2 pk4(f32x4 v) {
    uint2 u;
    u.x = __builtin_amdgcn_perm(__float_as_uint(v.y), __float_as_uint(v.x), 0x07060302u);
    u.y = __builtin_amdgcn_perm(__float_as_uint(v.w), __float_as_uint(v.z), 0x07060302u);
    return u;
}
__device__ __forceinline__ f32x4 up4(uint2 u) {
    f32x4 r;
    r.x = __uint_as_float(u.x << 16);
    r.y = __uint_as_float(u.x);
    r.z = __uint_as_float(u.y << 16);
    r.w = __uint_as_float(u.y);
    return r;
}
// o = tanh(a)*sigmoid(b), af = -2*log2e*a, ag = -log2e*b pre-scaled:
// E1=2^af=e^{-2a}, E2=2^ag=e^{-b}; o = (1-E1)/((1+E1)(1+E2))
__device__ __forceinline__ f32x4 gate4(f32x4 af, f32x4 ag) {
    f32x4 E1, E2;
    E1.x = fexp2(af.x); E1.y = fexp2(af.y); E1.z = fexp2(af.z); E1.w = fexp2(af.w);
    E2.x = fexp2(ag.x); E2.y = fexp2(ag.y); E2.z = fexp2(ag.z); E2.w = fexp2(ag.w);
    f32x4 d1  = E1 + splat(1.0f);
    f32x4 den = __builtin_elementwise_fma(E2, d1, d1);
    f32x4 num = splat(1.0f) - E1;
    f32x4 r;
    r.x = num.x * frcp(den.x); r.y = num.y * frcp(den.y);
    r.z = num.z * frcp(den.z); r.w = num.w * frcp(den.w);
    return r;
}
// conv1->relu->conv2->relu->mu-law expand; exp(|b|*ln256) == exp2(|b|*8)
__device__ __forceinline__ float mulaw(float v, float c1wv, float c1bv, float c2wv, float c2bv) {
    float a  = __builtin_fmaf(c1wv, fmaxf(v, 0.0f), c1bv);
    float b2 = __builtin_fmaf(c2wv, fmaxf(a, 0.0f), c2bv);
    float m  = fexp2(fabsf(b2) * 8.0f) - 1.0f;
    return copysignf(m * (1.0f / 255.0f), b2);
}

// One dilation cycle (10 layers, d=1..512). Thread owns 2 float4 groups
// (w=0: halo, w=1: valid) in fp32 registers; LDS holds bf16x2-packed taps,
// double-buffered, ONE barrier per layer. Inter-stage h handoff is packed
// bf16 (uint2). Reach-based halo skip: layer k's output is only needed at
// halo groups G >= 2^(k+1), so threads tid < 2<<k skip their w=0 work.
// Zero padding: global t<0 <=> (chunk==0 && w==0).
// NOTE: launch_bounds min-waves MUST stay at 4 — asking for 8 clamps the
// allocator to 32 VGPRs and causes a scratch-spill storm (round-5: +60 MB
// HBM writes/stage, 2x slowdown). 2 blocks/CU still happens naturally when
// the unconstrained allocation lands <= 64 VGPRs.
template <int STAGE>
__global__ __launch_bounds__(NTHREADS, 4)
void stage_kernel(const void* __restrict__ in_,
                  const float* __restrict__ cw, const float* __restrict__ cb,
                  const float* __restrict__ fw, const float* __restrict__ fb,
                  const float* __restrict__ gw, const float* __restrict__ gb,
                  const float* __restrict__ rw, const float* __restrict__ rb,
                  uint2* __restrict__ hout, float* __restrict__ skio,
                  const float* __restrict__ c1w, const float* __restrict__ c1b,
                  const float* __restrict__ c2w, const float* __restrict__ c2b,
                  float2* __restrict__ blockstats)
{
    __shared__ uint2 bufl[2][NGROUPS];       // 2 x 16 KB bf16x2 tap buffers
    __shared__ float red[NTHREADS / 64];

    const int tid = threadIdx.x;
    const int bid = blockIdx.x;
    const int row = bid / CHUNKS_PER_ROW;
    const int chunk = bid % CHUNKS_PER_ROW;
    const int rowbase = row * T_LEN;
    const int base_t = chunk * CHUNK;
    const bool first = (chunk == 0);

    // ---- load own groups (fp32 regs) + publish packed taps to buf 0 ----
    f32x4 h[2];
    if (STAGE == 0) {
        const float* inb = (const float*)in_ + rowbase + base_t - HALO;
        #pragma unroll
        for (int w = 0; w < 2; ++w) {
            int G = tid + w * NTHREADS;
            if (w == 0 && first) h[w] = splat(0.0f);
            else                 h[w] = *(const f32x4*)(inb + 4 * G);
            bufl[0][G] = pk4(h[w]);
        }
    } else {
        const uint2* inb = (const uint2*)in_ + ((rowbase + base_t - HALO) >> 2);
        #pragma unroll
        for (int w = 0; w < 2; ++w) {
            int G = tid + w * NTHREADS;
            uint2 u = (w == 0 && first) ? make_uint2(0u, 0u) : inb[G];
            bufl[0][G] = u;
            h[w] = up4(u);
        }
    }
    f32x4 sk;
    if (STAGE == 0) sk = splat(0.0f);
    else            sk = *(const f32x4*)(skio + rowbase + base_t + 4 * tid);
    __syncthreads();

    int c = 0;
    if (STAGE == 0) {
        // causal conv (d=1); weight for tap distance m is cw[4-m]
        const float c0 = cw[4], c1 = cw[3], c2 = cw[2], c3 = cw[1], c4 = cw[0];
        const float bb = cb[0];
        #pragma unroll
        for (int w = 0; w < 2; ++w) {
            int G = tid + w * NTHREADS;
            int gm = G - 1; if (w == 0) gm = gm < 0 ? 0 : gm;  // junk-in-halo OK
            f32x4 T = up4(bufl[0][gm]);
            f32x4 hw = h[w];
            f32x4 t1 = __builtin_shufflevector(T, hw, 3, 4, 5, 6);
            f32x4 t2 = __builtin_shufflevector(T, hw, 2, 3, 4, 5);
            f32x4 t3 = __builtin_shufflevector(T, hw, 1, 2, 3, 4);
            f32x4 acc = sfma(c0, hw, splat(bb));
            acc = sfma(c1, t1, acc);
            acc = sfma(c2, t2, acc);
            acc = sfma(c3, t3, acc);
            acc = sfma(c4, T, acc);
            if (w == 0 && first) acc = splat(0.0f);
            h[w] = acc;
            bufl[1][G] = pk4(acc);
        }
        __syncthreads();
        c = 1;
    }

    // ---- 10 dilated gated layers, one barrier each ----
    #pragma unroll
    for (int k = 0; k < 10; ++k) {
        const int d = 1 << k;
        const int L = STAGE * 10 + k;
        const float* fwL = fw + 5 * L;
        const float* gwL = gw + 5 * L;
        const float wf0 = fwL[4] * NEG2LOG2E, wf1 = fwL[3] * NEG2LOG2E,
                    wf2 = fwL[2] * NEG2LOG2E, wf3 = fwL[1] * NEG2LOG2E,
                    wf4 = fwL[0] * NEG2LOG2E;
        const float wg0 = gwL[4] * NEGLOG2E, wg1 = gwL[3] * NEGLOG2E,
                    wg2 = gwL[2] * NEGLOG2E, wg3 = gwL[1] * NEGLOG2E,
                    wg4 = gwL[0] * NEGLOG2E;
        const float fbv = fb[L] * NEG2LOG2E, gbv = gb[L] * NEGLOG2E;
        const float rwv = rw[L], rbv = rb[L];

        #pragma unroll
        for (int w = 0; w < 2; ++w) {
            if (w == 0 && k == 9) continue;          // halo never needed after last layer
            const int G = tid + w * NTHREADS;
            if (w == 0 && tid < (2 << k)) continue;  // reach expired for this group
            f32x4 hw = h[w];
            f32x4 t1, t2, t3, t4;
            if (d >= 4) {
                const int DG = d >> 2;               // taps stay group-aligned
                t1 = up4(bufl[c][G - DG]);
                t2 = up4(bufl[c][G - 2 * DG]);
                t3 = up4(bufl[c][G - 3 * DG]);
                t4 = up4(bufl[c][G - 4 * DG]);
            } else if (d == 1) {
                f32x4 T = up4(bufl[c][G - 1]);
                t1 = __builtin_shufflevector(T, hw, 3, 4, 5, 6);
                t2 = __builtin_shufflevector(T, hw, 2, 3, 4, 5);
                t3 = __builtin_shufflevector(T, hw, 1, 2, 3, 4);
                t4 = T;
            } else { // d == 2
                f32x4 T1 = up4(bufl[c][G - 1]);
                f32x4 T2 = up4(bufl[c][G - 2]);
                t1 = __builtin_shufflevector(T1, hw, 2, 3, 4, 5);
                t2 = T1;
                t3 = __builtin_shufflevector(T2, T1, 2, 3, 4, 5);
                t4 = T2;
            }
            f32x4 af = sfma(wf0, hw, splat(fbv));
            af = sfma(wf1, t1, af); af = sfma(wf2, t2, af);
            af = sfma(wf3, t3, af); af = sfma(wf4, t4, af);
            f32x4 ag = sfma(wg0, hw, splat(gbv));
            ag = sfma(wg1, t1, ag); ag = sfma(wg2, t2, ag);
            ag = sfma(wg3, t3, ag); ag = sfma(wg4, t4, ag);
            f32x4 o = gate4(af, ag);
            f32x4 nh = sfma(rwv, o, hw + splat(rbv));
            if (w == 0 && first) nh = splat(0.0f);   // keep t<0 padding exactly 0
            h[w] = nh;
            if (k < 9) bufl[c ^ 1][G] = pk4(nh);     // last layer never re-read
            if (w == 1) sk += o;
        }
        if (k < 9) __syncthreads();
        c ^= 1;
    }

    if (STAGE < 2) {
        hout[((rowbase + base_t) >> 2) + tid] = pk4(h[1]);   // packed bf16 handoff
        *(f32x4*)(skio + rowbase + base_t + 4 * tid) = sk;
    } else {
        // fused epilogue + per-block (max, sum-exp) stats
        const float c1wv = c1w[0], c1bv = c1b[0], c2wv = c2w[0], c2bv = c2b[0];
        f32x4 p;
        p.x = mulaw(sk.x, c1wv, c1bv, c2wv, c2bv);
        p.y = mulaw(sk.y, c1wv, c1bv, c2wv, c2bv);
        p.z = mulaw(sk.z, c1wv, c1bv, c2wv, c2bv);
        p.w = mulaw(sk.w, c1wv, c1bv, c2wv, c2bv);
        *(f32x4*)(skio + rowbase + base_t + 4 * tid) = p;

        float pmax = fmaxf(fmaxf(p.x, p.y), fmaxf(p.z, p.w));
        #pragma unroll
        for (int off = 32; off; off >>= 1) pmax = fmaxf(pmax, __shfl_xor(pmax, off, 64));
        if ((tid & 63) == 0) red[tid >> 6] = pmax;
        __syncthreads();
        float bmax = red[0];
        #pragma unroll
        for (int i = 1; i < NTHREADS / 64; ++i) bmax = fmaxf(bmax, red[i]);
        __syncthreads();   // red reused below

        float ps = fexp2((p.x - bmax) * LOG2E) + fexp2((p.y - bmax) * LOG2E)
                 + fexp2((p.z - bmax) * LOG2E) + fexp2((p.w - bmax) * LOG2E);
        #pragma unroll
        for (int off = 32; off; off >>= 1) ps += __shfl_xor(ps, off, 64);
        if ((tid & 63) == 0) red[tid >> 6] = ps;
        __syncthreads();
        if (tid == 0) {
            float s = 0.0f;
            #pragma unroll
            for (int i = 0; i < NTHREADS / 64; ++i) s += red[i];
            blockstats[bid] = make_float2(bmax, s);
        }
    }
}

// 8 blocks (one per row) x 64 threads: reduce 64 block-stats -> (rowmax, 1/rowsum)
__global__ __launch_bounds__(64)
void combine_kernel(const float2* __restrict__ bs, float2* __restrict__ rs)
{
    const int row = blockIdx.x;
    const int lane = threadIdx.x;
    float2 v = bs[row * CHUNKS_PER_ROW + lane];   // CHUNKS_PER_ROW == 64
    float bm = v.x, s = v.y;
    float m = bm;
    #pragma unroll
    for (int off = 32; off; off >>= 1) m = fmaxf(m, __shfl_xor(m, off, 64));
    float cc = s * fexp2((bm - m) * LOG2E);
    #pragma unroll
    for (int off = 32; off; off >>= 1) cc += __shfl_xor(cc, off, 64);
    if (lane == 0) rs[row] = make_float2(m, 1.0f / cc);
}

__global__ __launch_bounds__(NTHREADS)
void norm_kernel(float* __restrict__ p, const float2* __restrict__ rs)
{
    const int tid = threadIdx.x, bid = blockIdx.x;
    const int row = bid / CHUNKS_PER_ROW;
    const float2 st = rs[row];
    float* q = p + row * T_LEN + (bid % CHUNKS_PER_ROW) * CHUNK + 4 * tid;
    f32x4 v = *(const f32x4*)q;
    v.x = fexp2((v.x - st.x) * LOG2E) * st.y;
    v.y = fexp2((v.y - st.x) * LOG2E) * st.y;
    v.z = fexp2((v.z - st.x) * LOG2E) * st.y;
    v.w = fexp2((v.w - st.x) * LOG2E) * st.y;
    *(f32x4*)q = v;
}

extern "C" void kernel_launch(void* const* d_in, const int* in_sizes, int n_in,
                              void* d_out, int out_size, void* d_ws, size_t ws_size,
                              hipStream_t stream)
{
    (void)in_sizes; (void)n_in; (void)out_size; (void)ws_size;
    const float* x   = (const float*)d_in[0];
    const float* cw  = (const float*)d_in[1];
    const float* cb  = (const float*)d_in[2];
    const float* fw  = (const float*)d_in[3];
    const float* fb  = (const float*)d_in[4];
    const float* gw  = (const float*)d_in[5];
    const float* gb  = (const float*)d_in[6];
    const float* rw  = (const float*)d_in[7];
    const float* rb  = (const float*)d_in[8];
    const float* c1w = (const float*)d_in[9];
    const float* c1b = (const float*)d_in[10];
    const float* c2w = (const float*)d_in[11];
    const float* c2b = (const float*)d_in[12];
    float* out = (float*)d_out;

    const size_t NTOT = (size_t)B_SZ * T_LEN;
    uint2*  hA = (uint2*)d_ws;                                  // 4.2 MB packed bf16
    uint2*  hB = (uint2*)((char*)d_ws + NTOT * 2);              // 4.2 MB
    float2* bs = (float2*)((char*)d_ws + NTOT * 4);             // 4 KB
    float2* rs = (float2*)((char*)d_ws + NTOT * 4 + 8192);      // 64 B

    // d_out doubles as the skip accumulator between stages, then holds
    // pre-softmax values, then the final softmax output.
    stage_kernel<0><<<NBLOCKS, NTHREADS, 0, stream>>>(x,  cw, cb, fw, fb, gw, gb, rw, rb,
                                                      hA, out, c1w, c1b, c2w, c2b, bs);
    stage_kernel<1><<<NBLOCKS, NTHREADS, 0, stream>>>(hA, cw, cb, fw, fb, gw, gb, rw, rb,
                                                      hB, out, c1w, c1b, c2w, c2b, bs);
    stage_kernel<2><<<NBLOCKS, NTHREADS, 0, stream>>>(hB, cw, cb, fw, fb, gw, gb, rw, rb,
                                                      nullptr, out, c1w, c1b, c2w, c2b, bs);
    combine_kernel<<<B_SZ, 64, 0, stream>>>(bs, rs);
    norm_kernel<<<NBLOCKS, NTHREADS, 0, stream>>>(out, rs);
}

// Round 7
// 78.499 us; speedup vs baseline: 1.6544x; 1.5170x over previous
//
#include <hip/hip_runtime.h>

#define T_LEN 262144
#define B_SZ 8
#define CHUNK 8192
#define HALO 4096
#define NTHREADS 1024
#define NGROUPS ((CHUNK + HALO) / 4)    // 3072 float4-groups per block frame
#define CHUNKS_PER_ROW (T_LEN / CHUNK)  // 32
#define NBLOCKS (B_SZ * CHUNKS_PER_ROW) // 256
#define LOG2E 1.4426950408889634f
#define NEG2LOG2E (-2.8853900817779268f)
#define NEGLOG2E  (-1.4426950408889634f)

typedef float f32x2 __attribute__((ext_vector_type(2)));
typedef float f32x4 __attribute__((ext_vector_type(4)));

__device__ __forceinline__ float frcp(float x)  { return __builtin_amdgcn_rcpf(x); }
__device__ __forceinline__ float fexp2(float x) { return __builtin_amdgcn_exp2f(x); }
__device__ __forceinline__ f32x4 splat(float s) { f32x4 r = {s, s, s, s}; return r; }
__device__ __forceinline__ f32x2 pair(float s)  { f32x2 r = {s, s}; return r; }
__device__ __forceinline__ f32x2 lo2(f32x4 v)   { return __builtin_shufflevector(v, v, 0, 1); }
__device__ __forceinline__ f32x2 hi2(f32x4 v)   { return __builtin_shufflevector(v, v, 2, 3); }
__device__ __forceinline__ f32x4 cat4(f32x2 a, f32x2 b) {
    f32x4 r; r.x = a.x; r.y = a.y; r.z = b.x; r.w = b.y; return r;
}

// ---- packed-FP32 (VOP3P) primitives: 2 lanes of f32 per instruction ----
__device__ __forceinline__ f32x2 pkfma2(f32x2 a, f32x2 b, f32x2 c) {
    f32x2 d;
    asm("v_pk_fma_f32 %0, %1, %2, %3" : "=v"(d) : "v"(a), "v"(b), "v"(c));
    return d;
}
__device__ __forceinline__ f32x2 pkadd2(f32x2 a, f32x2 b) {
    f32x2 d;
    asm("v_pk_add_f32 %0, %1, %2" : "=v"(d) : "v"(a), "v"(b));
    return d;
}
__device__ __forceinline__ f32x2 pksub2(f32x2 a, f32x2 b) {  // a - b
    f32x2 d;
    asm("v_pk_add_f32 %0, %1, %2 neg_lo:[0,1] neg_hi:[0,1]" : "=v"(d) : "v"(a), "v"(b));
    return d;
}
__device__ __forceinline__ f32x2 pkmul2(f32x2 a, f32x2 b) {
    f32x2 d;
    asm("v_pk_mul_f32 %0, %1, %2" : "=v"(d) : "v"(a), "v"(b));
    return d;
}
// f32x4 wrappers (2 VOP3P each); s-variants broadcast a pre-splatted pair
__device__ __forceinline__ f32x4 pfma_s(f32x2 w, f32x4 v, f32x4 a) {
    return cat4(pkfma2(w, lo2(v), lo2(a)), pkfma2(w, hi2(v), hi2(a)));
}
__device__ __forceinline__ f32x4 pfma_v(f32x4 a, f32x4 b, f32x4 c) {
    return cat4(pkfma2(lo2(a), lo2(b), lo2(c)), pkfma2(hi2(a), hi2(b), hi2(c)));
}
__device__ __forceinline__ f32x4 padd_s(f32x2 s, f32x4 b) {
    return cat4(pkadd2(s, lo2(b)), pkadd2(s, hi2(b)));
}
__device__ __forceinline__ f32x4 padd_v(f32x4 a, f32x4 b) {
    return cat4(pkadd2(lo2(a), lo2(b)), pkadd2(hi2(a), hi2(b)));
}
__device__ __forceinline__ f32x4 psub_s(f32x2 s, f32x4 b) {  // s - b
    return cat4(pksub2(s, lo2(b)), pksub2(s, hi2(b)));
}
__device__ __forceinline__ f32x4 pmul_v(f32x4 a, f32x4 b) {
    return cat4(pkmul2(lo2(a), lo2(b)), pkmul2(hi2(a), hi2(b)));
}

// bf16x2 pack (truncating) via single v_perm_b32 per word; unpack leaves the
// neighbor's bits in the low mantissa (<=2^-9 relative noise, ~bf16 rounding)
__device__ __forceinline__ uint2 pk4(f32x4 v) {
    uint2 u;
    u.x = __builtin_amdgcn_perm(__float_as_uint(v.y), __float_as_uint(v.x), 0x07060302u);
    u.y = __builtin_amdgcn_perm(__float_as_uint(v.w), __float_as_uint(v.z), 0x07060302u);
    return u;
}
__device__ __forceinline__ f32x4 up4(uint2 u) {
    f32x4 r;
    r.x = __uint_as_float(u.x << 16);
    r.y = __uint_as_float(u.x);
    r.z = __uint_as_float(u.y << 16);
    r.w = __uint_as_float(u.y);
    return r;
}
// o = tanh(a)*sigmoid(b), af = -2*log2e*a, ag = -log2e*b pre-scaled:
// E1=2^af=e^{-2a}, E2=2^ag=e^{-b}; o = (1-E1)/((1+E1)(1+E2))
__device__ __forceinline__ f32x4 gate4(f32x4 af, f32x4 ag, f32x2 one) {
    f32x4 E1, E2, rc;
    E1.x = fexp2(af.x); E1.y = fexp2(af.y); E1.z = fexp2(af.z); E1.w = fexp2(af.w);
    E2.x = fexp2(ag.x); E2.y = fexp2(ag.y); E2.z = fexp2(ag.z); E2.w = fexp2(ag.w);
    f32x4 d1  = padd_s(one, E1);
    f32x4 den = pfma_v(E2, d1, d1);
    f32x4 num = psub_s(one, E1);
    rc.x = frcp(den.x); rc.y = frcp(den.y); rc.z = frcp(den.z); rc.w = frcp(den.w);
    return pmul_v(num, rc);
}
// conv1->relu->conv2->relu->mu-law expand; exp(|b|*ln256) == exp2(|b|*8)
__device__ __forceinline__ float mulaw(float v, float c1wv, float c1bv, float c2wv, float c2bv) {
    float a  = __builtin_fmaf(c1wv, fmaxf(v, 0.0f), c1bv);
    float b2 = __builtin_fmaf(c2wv, fmaxf(a, 0.0f), c2bv);
    float m  = fexp2(fabsf(b2) * 8.0f) - 1.0f;
    return copysignf(m * (1.0f / 255.0f), b2);
}

// One dilation cycle (10 layers, d=1..512). Thread owns 3 float4 groups
// (w=0: halo G=tid; w=1,2: valid G=tid+1024w) in fp32 registers; LDS holds
// bf16x2-packed taps, double-buffered, ONE barrier per layer. Inter-stage h
// handoff is packed bf16. Reach-based halo skip: layer k's output is only
// needed at halo groups G >= 2^(k+1), so threads tid < 2<<k skip w=0 work;
// readers never touch skipped groups and no index underflows.
// Zero padding: global t<0 <=> (chunk==0 && w==0).
// NOTE: launch_bounds min-waves MUST stay at 4 — asking for 8 clamps the
// allocator to 32 VGPRs and causes a scratch-spill storm (round 5: +60 MB
// HBM writes/stage, 2x slowdown).
template <int STAGE>
__global__ __launch_bounds__(NTHREADS, 4)
void stage_kernel(const void* __restrict__ in_,
                  const float* __restrict__ cw, const float* __restrict__ cb,
                  const float* __restrict__ fw, const float* __restrict__ fb,
                  const float* __restrict__ gw, const float* __restrict__ gb,
                  const float* __restrict__ rw, const float* __restrict__ rb,
                  uint2* __restrict__ hout, float* __restrict__ skio,
                  const float* __restrict__ c1w, const float* __restrict__ c1b,
                  const float* __restrict__ c2w, const float* __restrict__ c2b,
                  float2* __restrict__ blockstats)
{
    __shared__ uint2 bufl[2][NGROUPS];       // 2 x 24 KB bf16x2 tap buffers
    __shared__ float red[NTHREADS / 64];

    const int tid = threadIdx.x;
    const int bid = blockIdx.x;
    const int row = bid / CHUNKS_PER_ROW;
    const int chunk = bid % CHUNKS_PER_ROW;
    const int rowbase = row * T_LEN;
    const int base_t = chunk * CHUNK;
    const bool first = (chunk == 0);

    // ---- load own groups (fp32 regs) + publish packed taps to buf 0 ----
    f32x4 h[3];
    if (STAGE == 0) {
        const float* inb = (const float*)in_ + rowbase + base_t - HALO;
        #pragma unroll
        for (int w = 0; w < 3; ++w) {
            int G = tid + w * NTHREADS;
            if (w == 0 && first) h[w] = splat(0.0f);
            else                 h[w] = *(const f32x4*)(inb + 4 * G);
            bufl[0][G] = pk4(h[w]);
        }
    } else {
        const uint2* inb = (const uint2*)in_ + ((rowbase + base_t - HALO) >> 2);
        #pragma unroll
        for (int w = 0; w < 3; ++w) {
            int G = tid + w * NTHREADS;
            uint2 u = (w == 0 && first) ? make_uint2(0u, 0u) : inb[G];
            bufl[0][G] = u;
            h[w] = up4(u);
        }
    }
    f32x4 sk[2];
    if (STAGE == 0) { sk[0] = splat(0.0f); sk[1] = splat(0.0f); }
    else {
        sk[0] = *(const f32x4*)(skio + rowbase + base_t + 4 * tid);
        sk[1] = *(const f32x4*)(skio + rowbase + base_t + 4096 + 4 * tid);
    }
    __syncthreads();

    int c = 0;
    if (STAGE == 0) {
        // causal conv (d=1); weight for tap distance m is cw[4-m]
        f32x2 CW[5];
        #pragma unroll
        for (int j = 0; j < 5; ++j) CW[j] = pair(cw[4 - j]);
        const f32x4 BB = splat(cb[0]);
        #pragma unroll
        for (int w = 0; w < 3; ++w) {
            int G = tid + w * NTHREADS;
            int gm = G - 1; if (w == 0) gm = gm < 0 ? 0 : gm;  // junk-in-halo OK
            f32x4 T = up4(bufl[0][gm]);
            f32x4 hw = h[w];
            f32x4 t1 = __builtin_shufflevector(T, hw, 3, 4, 5, 6);
            f32x4 t2 = __builtin_shufflevector(T, hw, 2, 3, 4, 5);
            f32x4 t3 = __builtin_shufflevector(T, hw, 1, 2, 3, 4);
            f32x4 acc = pfma_s(CW[0], hw, BB);
            acc = pfma_s(CW[1], t1, acc);
            acc = pfma_s(CW[2], t2, acc);
            acc = pfma_s(CW[3], t3, acc);
            acc = pfma_s(CW[4], T, acc);
            if (w == 0 && first) acc = splat(0.0f);
            h[w] = acc;
            bufl[1][G] = pk4(acc);
        }
        __syncthreads();
        c = 1;
    }

    const f32x2 ONE = pair(1.0f);

    // ---- 10 dilated gated layers, one barrier each ----
    #pragma unroll
    for (int k = 0; k < 10; ++k) {
        const int d = 1 << k;
        const int L = STAGE * 10 + k;
        const float* fwL = fw + 5 * L;
        const float* gwL = gw + 5 * L;
        f32x2 WF[5], WG[5];
        #pragma unroll
        for (int j = 0; j < 5; ++j) {          // tap j*d uses weight index 4-j
            WF[j] = pair(fwL[4 - j] * NEG2LOG2E);
            WG[j] = pair(gwL[4 - j] * NEGLOG2E);
        }
        const f32x4 FB = splat(fb[L] * NEG2LOG2E), GB = splat(gb[L] * NEGLOG2E);
        const f32x2 RW = pair(rw[L]), RB = pair(rb[L]);

        #pragma unroll
        for (int w = 0; w < 3; ++w) {
            const int G = tid + w * NTHREADS;
            if (w == 0 && tid < (2 << k)) continue;  // reach expired (k=9: all of w=0)
            f32x4 hw = h[w];
            f32x4 t1, t2, t3, t4;
            if (d >= 4) {
                const int DG = d >> 2;               // taps stay group-aligned
                t1 = up4(bufl[c][G - DG]);
                t2 = up4(bufl[c][G - 2 * DG]);
                t3 = up4(bufl[c][G - 3 * DG]);
                t4 = up4(bufl[c][G - 4 * DG]);
            } else if (d == 1) {
                f32x4 T = up4(bufl[c][G - 1]);
                t1 = __builtin_shufflevector(T, hw, 3, 4, 5, 6);
                t2 = __builtin_shufflevector(T, hw, 2, 3, 4, 5);
                t3 = __builtin_shufflevector(T, hw, 1, 2, 3, 4);
                t4 = T;
            } else { // d == 2
                f32x4 T1 = up4(bufl[c][G - 1]);
                f32x4 T2 = up4(bufl[c][G - 2]);
                t1 = __builtin_shufflevector(T1, hw, 2, 3, 4, 5);
                t2 = T1;
                t3 = __builtin_shufflevector(T2, T1, 2, 3, 4, 5);
                t4 = T2;
            }
            f32x4 af = pfma_s(WF[0], hw, FB);
            af = pfma_s(WF[1], t1, af); af = pfma_s(WF[2], t2, af);
            af = pfma_s(WF[3], t3, af); af = pfma_s(WF[4], t4, af);
            f32x4 ag = pfma_s(WG[0], hw, GB);
            ag = pfma_s(WG[1], t1, ag); ag = pfma_s(WG[2], t2, ag);
            ag = pfma_s(WG[3], t3, ag); ag = pfma_s(WG[4], t4, ag);
            f32x4 o = gate4(af, ag, ONE);
            f32x4 nh = pfma_s(RW, o, padd_s(RB, hw));
            if (w == 0 && first) nh = splat(0.0f);   // keep t<0 padding exactly 0
            h[w] = nh;
            if (k < 9) bufl[c ^ 1][G] = pk4(nh);     // last layer never re-read
            if (w == 1) sk[0] = padd_v(sk[0], o);
            if (w == 2) sk[1] = padd_v(sk[1], o);
        }
        if (k < 9) __syncthreads();
        c ^= 1;
    }

    if (STAGE < 2) {
        uint2* hp = hout + ((rowbase + base_t) >> 2);
        hp[tid]        = pk4(h[1]);                  // packed bf16 handoff
        hp[tid + 1024] = pk4(h[2]);
        *(f32x4*)(skio + rowbase + base_t + 4 * tid)        = sk[0];
        *(f32x4*)(skio + rowbase + base_t + 4096 + 4 * tid) = sk[1];
    } else {
        // fused epilogue + per-block (max, sum-exp) stats
        const float c1wv = c1w[0], c1bv = c1b[0], c2wv = c2w[0], c2bv = c2b[0];
        f32x4 p1, p2;
        p1.x = mulaw(sk[0].x, c1wv, c1bv, c2wv, c2bv);
        p1.y = mulaw(sk[0].y, c1wv, c1bv, c2wv, c2bv);
        p1.z = mulaw(sk[0].z, c1wv, c1bv, c2wv, c2bv);
        p1.w = mulaw(sk[0].w, c1wv, c1bv, c2wv, c2bv);
        p2.x = mulaw(sk[1].x, c1wv, c1bv, c2wv, c2bv);
        p2.y = mulaw(sk[1].y, c1wv, c1bv, c2wv, c2bv);
        p2.z = mulaw(sk[1].z, c1wv, c1bv, c2wv, c2bv);
        p2.w = mulaw(sk[1].w, c1wv, c1bv, c2wv, c2bv);
        *(f32x4*)(skio + rowbase + base_t + 4 * tid)        = p1;
        *(f32x4*)(skio + rowbase + base_t + 4096 + 4 * tid) = p2;

        float pmax = fmaxf(fmaxf(fmaxf(p1.x, p1.y), fmaxf(p1.z, p1.w)),
                           fmaxf(fmaxf(p2.x, p2.y), fmaxf(p2.z, p2.w)));
        #pragma unroll
        for (int off = 32; off; off >>= 1) pmax = fmaxf(pmax, __shfl_xor(pmax, off, 64));
        if ((tid & 63) == 0) red[tid >> 6] = pmax;
        __syncthreads();
        float bmax = red[0];
        #pragma unroll
        for (int i = 1; i < NTHREADS / 64; ++i) bmax = fmaxf(bmax, red[i]);
        __syncthreads();   // red reused below

        float ps = fexp2((p1.x - bmax) * LOG2E) + fexp2((p1.y - bmax) * LOG2E)
                 + fexp2((p1.z - bmax) * LOG2E) + fexp2((p1.w - bmax) * LOG2E)
                 + fexp2((p2.x - bmax) * LOG2E) + fexp2((p2.y - bmax) * LOG2E)
                 + fexp2((p2.z - bmax) * LOG2E) + fexp2((p2.w - bmax) * LOG2E);
        #pragma unroll
        for (int off = 32; off; off >>= 1) ps += __shfl_xor(ps, off, 64);
        if ((tid & 63) == 0) red[tid >> 6] = ps;
        __syncthreads();
        if (tid == 0) {
            float s = 0.0f;
            #pragma unroll
            for (int i = 0; i < NTHREADS / 64; ++i) s += red[i];
            blockstats[bid] = make_float2(bmax, s);
        }
    }
}

// 8 blocks (one per row) x 64 threads: reduce 32 block-stats -> (rowmax, 1/rowsum)
__global__ __launch_bounds__(64)
void combine_kernel(const float2* __restrict__ bs, float2* __restrict__ rs)
{
    const int row = blockIdx.x;
    const int lane = threadIdx.x;
    float bm = -3.0e38f, s = 0.0f;
    if (lane < CHUNKS_PER_ROW) {
        float2 v = bs[row * CHUNKS_PER_ROW + lane];
        bm = v.x; s = v.y;
    }
    float m = bm;
    #pragma unroll
    for (int off = 32; off; off >>= 1) m = fmaxf(m, __shfl_xor(m, off, 64));
    float cc = s * fexp2((bm - m) * LOG2E);
    #pragma unroll
    for (int off = 32; off; off >>= 1) cc += __shfl_xor(cc, off, 64);
    if (lane == 0) rs[row] = make_float2(m, 1.0f / cc);
}

__global__ __launch_bounds__(NTHREADS)
void norm_kernel(float* __restrict__ p, const float2* __restrict__ rs)
{
    const int tid = threadIdx.x, bid = blockIdx.x;
    const int row = bid / CHUNKS_PER_ROW;
    const float2 st = rs[row];
    const int base = row * T_LEN + (bid % CHUNKS_PER_ROW) * CHUNK + 4 * tid;
    #pragma unroll
    for (int part = 0; part < 2; ++part) {
        float* q = p + base + part * 4096;
        f32x4 v = *(const f32x4*)q;
        v.x = fexp2((v.x - st.x) * LOG2E) * st.y;
        v.y = fexp2((v.y - st.x) * LOG2E) * st.y;
        v.z = fexp2((v.z - st.x) * LOG2E) * st.y;
        v.w = fexp2((v.w - st.x) * LOG2E) * st.y;
        *(f32x4*)q = v;
    }
}

extern "C" void kernel_launch(void* const* d_in, const int* in_sizes, int n_in,
                              void* d_out, int out_size, void* d_ws, size_t ws_size,
                              hipStream_t stream)
{
    (void)in_sizes; (void)n_in; (void)out_size; (void)ws_size;
    const float* x   = (const float*)d_in[0];
    const float* cw  = (const float*)d_in[1];
    const float* cb  = (const float*)d_in[2];
    const float* fw  = (const float*)d_in[3];
    const float* fb  = (const float*)d_in[4];
    const float* gw  = (const float*)d_in[5];
    const float* gb  = (const float*)d_in[6];
    const float* rw  = (const float*)d_in[7];
    const float* rb  = (const float*)d_in[8];
    const float* c1w = (const float*)d_in[9];
    const float* c1b = (const float*)d_in[10];
    const float* c2w = (const float*)d_in[11];
    const float* c2b = (const float*)d_in[12];
    float* out = (float*)d_out;

    const size_t NTOT = (size_t)B_SZ * T_LEN;
    uint2*  hA = (uint2*)d_ws;                                  // 4.2 MB packed bf16
    uint2*  hB = (uint2*)((char*)d_ws + NTOT * 2);              // 4.2 MB
    float2* bs = (float2*)((char*)d_ws + NTOT * 4);             // 2 KB
    float2* rs = (float2*)((char*)d_ws + NTOT * 4 + 8192);      // 64 B

    // d_out doubles as the skip accumulator between stages, then holds
    // pre-softmax values, then the final softmax output.
    stage_kernel<0><<<NBLOCKS, NTHREADS, 0, stream>>>(x,  cw, cb, fw, fb, gw, gb, rw, rb,
                                                      hA, out, c1w, c1b, c2w, c2b, bs);
    stage_kernel<1><<<NBLOCKS, NTHREADS, 0, stream>>>(hA, cw, cb, fw, fb, gw, gb, rw, rb,
                                                      hB, out, c1w, c1b, c2w, c2b, bs);
    stage_kernel<2><<<NBLOCKS, NTHREADS, 0, stream>>>(hB, cw, cb, fw, fb, gw, gb, rw, rb,
                                                      nullptr, out, c1w, c1b, c2w, c2b, bs);
    combine_kernel<<<B_SZ, 64, 0, stream>>>(bs, rs);
    norm_kernel<<<NBLOCKS, NTHREADS, 0, stream>>>(out, rs);
}